// Round 4
// baseline (756.014 us; speedup 1.0000x reference)
//
#include <hip/hip_runtime.h>
#include <hip/hip_bf16.h>
#include <stdint.h>

#define DIM 2048
#define NEXP 8
#define NTOK 8192
#define KSEL 6

#define DENSE_BLOCKS 1024        // 16 x-tiles * 64 y-tiles
#define COMP_X 16
#define COMP_Y 32                // covers cnt[e] up to 4096 (mean 2048)
#define COMP_BLOCKS (COMP_X * COMP_Y * NEXP)

typedef short bf16x8 __attribute__((ext_vector_type(8)));
typedef float f32x4 __attribute__((ext_vector_type(4)));
typedef const __attribute__((address_space(1))) unsigned int GU32;
typedef __attribute__((address_space(3))) unsigned int LU32;

__device__ __forceinline__ unsigned short f2b(float f) {
  union { float f; uint32_t u; } v; v.f = f;
  return (unsigned short)((v.u + 0x7fffu + ((v.u >> 16) & 1u)) >> 16);
}

__global__ void zero_cnt_kernel(int* cnt) {
  if (threadIdx.x < NEXP) cnt[threadIdx.x] = 0;
}

// One wave per token: fp32 gate scores (exact top-k w/ jax tie-break),
// record the 2 EXCLUDED experts, build per-expert complement buckets,
// write the bf16 cast of x.
__global__ __launch_bounds__(256) void gate_kernel(
    const float* __restrict__ x, const float* __restrict__ Wg,
    const float* __restrict__ bg, unsigned short* __restrict__ xB,
    int* __restrict__ cnt, int* __restrict__ list, int* __restrict__ exPair) {
  int t = threadIdx.x;
  int w = t >> 6, l = t & 63;
  int n = blockIdx.x * 4 + w;
  const float* xr = x + (size_t)n * DIM;
  float xv[32];
#pragma unroll
  for (int j = 0; j < 8; ++j) {
    float4 v = *(const float4*)(xr + 4 * l + 256 * j);
    xv[4 * j + 0] = v.x; xv[4 * j + 1] = v.y;
    xv[4 * j + 2] = v.z; xv[4 * j + 3] = v.w;
  }
  unsigned short* xbr = xB + (size_t)n * DIM;
#pragma unroll
  for (int j = 0; j < 8; ++j) {
    ushort4 o;
    o.x = f2b(xv[4 * j + 0]); o.y = f2b(xv[4 * j + 1]);
    o.z = f2b(xv[4 * j + 2]); o.w = f2b(xv[4 * j + 3]);
    *(ushort4*)(xbr + 4 * l + 256 * j) = o;
  }
  float sc[NEXP];
#pragma unroll
  for (int e = 0; e < NEXP; ++e) {
    const float* wr = Wg + e * DIM;
    float s = 0.f;
#pragma unroll
    for (int j = 0; j < 8; ++j) {
      float4 v = *(const float4*)(wr + 4 * l + 256 * j);
      s += xv[4 * j + 0] * v.x + xv[4 * j + 1] * v.y +
           xv[4 * j + 2] * v.z + xv[4 * j + 3] * v.w;
    }
#pragma unroll
    for (int off = 32; off > 0; off >>= 1) s += __shfl_xor(s, off, 64);
    sc[e] = s + bg[e];
  }
  if (l == 0) {
    int ex[2]; int ne = 0;
#pragma unroll
    for (int e = 0; e < NEXP; ++e) {
      int rank = 0;
#pragma unroll
      for (int j = 0; j < NEXP; ++j)
        rank += (sc[j] > sc[e]) || (sc[j] == sc[e] && j < e);
      if (rank >= KSEL) { if (ne < 2) ex[ne] = e; ++ne; }
    }
    exPair[2 * n + 0] = ex[0];
    exPair[2 * n + 1] = ex[1];
    int p0 = atomicAdd(&cnt[ex[0]], 1); list[ex[0] * NTOK + p0] = n;
    int p1 = atomicAdd(&cnt[ex[1]], 1); list[ex[1] * NTOK + p1] = n;
  }
}

// We fp32 -> per-expert bf16 + Wsum bf16, single pass.
__global__ __launch_bounds__(256) void convert_kernel(
    const float* __restrict__ We, unsigned short* __restrict__ WeB,
    unsigned short* __restrict__ WsumB) {
  size_t p = ((size_t)blockIdx.x * 256 + threadIdx.x) * 4;
  float sx = 0.f, sy = 0.f, sz = 0.f, sw = 0.f;
#pragma unroll
  for (int e = 0; e < NEXP; ++e) {
    float4 v = *(const float4*)(We + (size_t)e * DIM * DIM + p);
    sx += v.x; sy += v.y; sz += v.z; sw += v.w;
    ushort4 o; o.x = f2b(v.x); o.y = f2b(v.y); o.z = f2b(v.z); o.w = f2b(v.w);
    *(ushort4*)(WeB + (size_t)e * DIM * DIM + p) = o;
  }
  ushort4 os; os.x = f2b(sx); os.y = f2b(sy); os.z = f2b(sz); os.w = f2b(sw);
  *(ushort4*)(WsumB + p) = os;
}

__global__ void besum_kernel(const float* __restrict__ be, float* __restrict__ besum) {
  int f = blockIdx.x * 256 + threadIdx.x;
  float s = 0.f;
#pragma unroll
  for (int e = 0; e < NEXP; ++e) s += be[e * DIM + f];
  besum[f] = s;
}

// out[n,f] = besum[f] - be[ex0,f] - be[ex1,f]  (bias base; GEMMs atomically
// accumulate on top). Pure 64 MB write, be/besum L2-resident.
__global__ __launch_bounds__(256) void init_out(
    const float* __restrict__ besum, const float* __restrict__ be,
    const int* __restrict__ exPair, float* __restrict__ out) {
  int gid = blockIdx.x * 256 + threadIdx.x;
  int n = gid >> 9;              // 512 float4 per token row
  int j = gid & 511;
  int e0 = exPair[2 * n + 0], e1 = exPair[2 * n + 1];
  float4 bs = ((const float4*)besum)[j];
  float4 b0 = ((const float4*)be)[e0 * 512 + j];
  float4 b1 = ((const float4*)be)[e1 * 512 + j];
  float4 o;
  o.x = bs.x - b0.x - b1.x; o.y = bs.y - b0.y - b1.y;
  o.z = bs.z - b0.z - b1.z; o.w = bs.w - b0.w - b1.w;
  ((float4*)out)[gid] = o;
}

// Fused GEMM. Blocks [0, 1024): dense out += x.Wsum^T (XCD-pairing swizzle).
// Blocks [1024, 5120): complement out -= gathered x rows . We[e]^T.
// 128x128 tile, BK=64 (32 MFMA per barrier-pair), 16x16x32 bf16 MFMA,
// global_load_lds w=16, XOR bank swizzle.
// LDS exactly 32768 B (sRows eliminated -> list read direct): 5 blocks/CU.
// Comp grid swizzled so the 16 x-blocks sharing one gathered A-tile are
// co-resident on one XCD (A-tile L2-resident once per XCD).
__global__ __launch_bounds__(256, 4) void gemm_fused(
    const unsigned short* __restrict__ A, const unsigned short* __restrict__ WsumB,
    const unsigned short* __restrict__ WeB,
    const int* __restrict__ cnt, const int* __restrict__ list,
    float* __restrict__ out) {
  __shared__ unsigned short sA[128 * 64];
  __shared__ unsigned short sB[128 * 64];
  int bid = blockIdx.x;
  int t = threadIdx.x;
  int w = t >> 6, l = t & 63;
  int wm = w & 1, wn = w >> 1;
  int quad = l >> 4, lr = l & 15;
  int cs = (l & 7) ^ ((l >> 3) & 7);   // staging k-granule swizzle

  bool dense = bid < DENSE_BLOCKS;
  int m0, f0, c = 0, lbase = 0;
  const unsigned short* Bb;
  size_t rowOffA[4], rowOffB[4];
  if (dense) {
    int xcd = bid & 7, s = bid >> 3;
    f0 = ((xcd << 1) | (s & 1)) * 128;
    m0 = (s >> 1) * 128;
    Bb = WsumB;
#pragma unroll
    for (int i = 0; i < 4; ++i)
      rowOffA[i] = (size_t)(m0 + i * 32 + w * 8 + (l >> 3)) * DIM;
  } else {
    int cb = bid - DENSE_BLOCKS;
    // XCD swizzle: 16 x-blocks of one (e,y) group share xcd = cb&7 and a
    // 128-bid span (co-resident with ~128 blocks/XCD).
    int xcd = cb & 7, j = cb >> 3;
    int x = j & 15;
    int g = ((j >> 4) << 3) | xcd;     // 0..255
    int e = g >> 5, y = g & 31;
    c = cnt[e];
    m0 = y * 128;
    if (m0 >= c) return;
    f0 = x * 128;
    Bb = WeB + (size_t)e * DIM * DIM;
    lbase = e * NTOK;
#pragma unroll
    for (int i = 0; i < 4; ++i) {
      int idx = m0 + i * 32 + w * 8 + (l >> 3);
      if (idx >= c) idx = c - 1;
      rowOffA[i] = (size_t)list[lbase + idx] * DIM;
    }
  }
#pragma unroll
  for (int i = 0; i < 4; ++i)
    rowOffB[i] = (size_t)(f0 + i * 32 + w * 8 + (l >> 3)) * DIM;

  f32x4 acc[4][4];
#pragma unroll
  for (int mi = 0; mi < 4; ++mi)
#pragma unroll
    for (int ni = 0; ni < 4; ++ni) {
      acc[mi][ni][0] = 0.f; acc[mi][ni][1] = 0.f;
      acc[mi][ni][2] = 0.f; acc[mi][ni][3] = 0.f;
    }

  for (int k0 = 0; k0 < DIM; k0 += 64) {
#pragma unroll
    for (int i = 0; i < 4; ++i) {
      __builtin_amdgcn_global_load_lds((GU32*)(A + rowOffA[i] + k0 + cs * 8),
          (LU32*)(sA + (i * 32 + w * 8) * 64), 16, 0, 0);
      __builtin_amdgcn_global_load_lds((GU32*)(Bb + rowOffB[i] + k0 + cs * 8),
          (LU32*)(sB + (i * 32 + w * 8) * 64), 16, 0, 0);
    }
    __syncthreads();
#pragma unroll
    for (int ks = 0; ks < 2; ++ks) {
      bf16x8 aF[4], bF[4];
#pragma unroll
      for (int mi = 0; mi < 4; ++mi)
        aF[mi] = *(const bf16x8*)(sA + (wm * 64 + mi * 16 + lr) * 64 +
                                  (((ks << 2) | quad) ^ (lr & 7)) * 8);
#pragma unroll
      for (int ni = 0; ni < 4; ++ni)
        bF[ni] = *(const bf16x8*)(sB + (wn * 64 + ni * 16 + lr) * 64 +
                                  (((ks << 2) | quad) ^ (lr & 7)) * 8);
#pragma unroll
      for (int mi = 0; mi < 4; ++mi)
#pragma unroll
        for (int ni = 0; ni < 4; ++ni)
          acc[mi][ni] = __builtin_amdgcn_mfma_f32_16x16x32_bf16(aF[mi], bF[ni], acc[mi][ni], 0, 0, 0);
    }
    __syncthreads();
  }

  if (dense) {
#pragma unroll
    for (int mi = 0; mi < 4; ++mi) {
#pragma unroll
      for (int i = 0; i < 4; ++i) {
        int lrow = wm * 64 + mi * 16 + quad * 4 + i;
        float* orow = out + (size_t)(m0 + lrow) * DIM;
#pragma unroll
        for (int ni = 0; ni < 4; ++ni) {
          int col = f0 + wn * 64 + ni * 16 + lr;
          unsafeAtomicAdd(orow + col, acc[mi][ni][i]);
        }
      }
    }
  } else {
#pragma unroll
    for (int mi = 0; mi < 4; ++mi) {
#pragma unroll
      for (int i = 0; i < 4; ++i) {
        int lrow = wm * 64 + mi * 16 + quad * 4 + i;
        if (m0 + lrow < c) {
          float* orow = out + (size_t)list[lbase + m0 + lrow] * DIM;
#pragma unroll
          for (int ni = 0; ni < 4; ++ni) {
            int col = f0 + wn * 64 + ni * 16 + lr;
            unsafeAtomicAdd(orow + col, -acc[mi][ni][i]);
          }
        }
      }
    }
  }
}

extern "C" void kernel_launch(void* const* d_in, const int* in_sizes, int n_in,
                              void* d_out, int out_size, void* d_ws, size_t ws_size,
                              hipStream_t stream) {
  const float* x  = (const float*)d_in[0];
  const float* Wg = (const float*)d_in[1];
  const float* bg = (const float*)d_in[2];
  const float* We = (const float*)d_in[3];
  const float* be = (const float*)d_in[4];
  float* out = (float*)d_out;

  char* ws = (char*)d_ws;
  unsigned short* xB = (unsigned short*)ws;    ws += (size_t)NTOK * DIM * 2;
  unsigned short* WeB = (unsigned short*)ws;   ws += (size_t)NEXP * DIM * DIM * 2;
  unsigned short* WsumB = (unsigned short*)ws; ws += (size_t)DIM * DIM * 2;
  float* besum = (float*)ws;                   ws += DIM * 4;
  int* cnt = (int*)ws;                         ws += 32;
  int* list = (int*)ws;                        ws += (size_t)NEXP * NTOK * 4;
  int* exPair = (int*)ws;                      ws += (size_t)NTOK * 2 * 4;

  zero_cnt_kernel<<<1, 64, 0, stream>>>(cnt);
  gate_kernel<<<NTOK / 4, 256, 0, stream>>>(x, Wg, bg, xB, cnt, list, exPair);
  convert_kernel<<<(DIM * DIM) / (4 * 256), 256, 0, stream>>>(We, WeB, WsumB);
  besum_kernel<<<DIM / 256, 256, 0, stream>>>(be, besum);
  init_out<<<(NTOK * DIM / 4) / 256, 256, 0, stream>>>(besum, be, exPair, out);
  gemm_fused<<<DENSE_BLOCKS + COMP_BLOCKS, 256, 0, stream>>>(xB, WsumB, WeB, cnt, list, out);
}